// Round 12
// baseline (247.502 us; speedup 1.0000x reference)
//
#include <hip/hip_runtime.h>
#include <stdint.h>

// Problem constants (fixed by the reference).
#define T_TABLES 26
#define V_VOCAB  1000
#define D_DIM    128
#define B_BATCH  8192
#define L_BAG    8

#define SEG4   (D_DIM / 4)                   // 32 f32x4 per 128-float row
#define ROW4   ((T_TABLES + 1) * SEG4)       // 864 f32x4 per output row
#define NH     4                             // batch quarters per slice
#define HB     (B_BATCH / NH)                // 2048 rows per gather block
#define TS     (T_TABLES * 2)                // 52 (table, 64-dim-slice) pairs
#define GBLK   (TS * NH)                     // 208 gather blocks
#define NBLK   256                           // 1 block per CU
#define NDEN   (NBLK - GBLK)                 // 48 dense-copy blocks
#define NTHR   512
#define REPA   8                             // probe repeat factors (to rise
#define REPB   8                             //  above the 64 us memset rows)

typedef float    f32x4 __attribute__((ext_vector_type(4)));
typedef _Float16 f16x8 __attribute__((ext_vector_type(8)));

// ---------------- ABLATION ROUND ----------------
// R6/R10/R11 all plateau at 29-30 us despite changing LDS instr count (2x),
// idx pipelining, and store cache policy. Three failed predictions -> measure.
// probe_store = idx + output-write pattern only (x8).
// probe_lds   = stage + LDS gather chain only (x8).
// Real R11 kernel runs LAST -> d_out correct.

__global__ __launch_bounds__(NTHR)
void probe_store(const int* __restrict__ indices,
                 const float* __restrict__ to_cat,
                 float* __restrict__ out)
{
    const int bid = blockIdx.x, tid = threadIdx.x;
    if (bid < GBLK) {
        const int h = bid / TS, ts = bid - h * TS;
        const int t = ts >> 1, s = ts & 1, b0 = h * HB;
        const int w = tid >> 6, lane = tid & 63, grp = lane >> 3, c = lane & 7;
        const int* ibase = indices + t * (B_BATCH * L_BAG);
        f32x4* o4 = reinterpret_cast<f32x4*>(out)
                  + (size_t)(t + 1) * SEG4 + s * 16 + c;
        for (int rep = 0; rep < REPA; ++rep) {
            int row = b0 + w * 8 + grp;
            for (int i = 0; i < HB / 64; ++i) {
                const int4* ib = reinterpret_cast<const int4*>(ibase + row * L_BAG);
                const int4 ia = ib[0];
                const int4 iz = ib[1];
                f32x4 vA, vB;   // value-dependent on idx loads (keeps them live)
                vA.x = (float)ia.x; vA.y = (float)ia.y;
                vA.z = (float)ia.z; vA.w = (float)(ia.w + rep);
                vB.x = (float)iz.x; vB.y = (float)iz.y;
                vB.z = (float)iz.z; vB.w = (float)(iz.w + rep);
                o4[(size_t)row * ROW4]     = vA;
                o4[(size_t)row * ROW4 + 8] = vB;
                row += 64;
            }
            asm volatile("" ::: "memory");   // no cross-rep store elimination
        }
    } else {
        const int db = bid - GBLK;
        const f32x4* c4 = reinterpret_cast<const f32x4*>(to_cat);
        f32x4* o4 = reinterpret_cast<f32x4*>(out);
        for (int rep = 0; rep < REPA; ++rep) {
            for (int x = db * NTHR + tid; x < B_BATCH * SEG4; x += NDEN * NTHR) {
                const int r = x >> 5, cc = x & 31;
                o4[(size_t)r * ROW4 + cc] = c4[x];
            }
            asm volatile("" ::: "memory");
        }
    }
}

__global__ __launch_bounds__(NTHR)
void probe_lds(const int* __restrict__ indices,
               const float* __restrict__ tables,
               float* __restrict__ out)
{
    __shared__ uint4 slice[V_VOCAB * 8];
    const int bid = blockIdx.x, tid = threadIdx.x;
    if (bid >= GBLK) return;
    const int h = bid / TS, ts = bid - h * TS;
    const int t = ts >> 1, s = ts & 1, b0 = h * HB;
    {
        const int r0 = tid >> 3, c = tid & 7;
        const float* srcA = tables + (size_t)t * (V_VOCAB * D_DIM) + s * 64 + c * 4;
        #pragma unroll 4
        for (int it = 0; it < 16; ++it) {
            const int r = it * 64 + r0;
            if (r < V_VOCAB) {
                const float* pr = srcA + (size_t)r * D_DIM;
                const f32x4 a = *reinterpret_cast<const f32x4*>(pr);
                const f32x4 e = *reinterpret_cast<const f32x4*>(pr + 32);
                uint4 u;
                u.x = __builtin_bit_cast(uint32_t, __builtin_amdgcn_cvt_pkrtz(a.x, a.y));
                u.y = __builtin_bit_cast(uint32_t, __builtin_amdgcn_cvt_pkrtz(a.z, a.w));
                u.z = __builtin_bit_cast(uint32_t, __builtin_amdgcn_cvt_pkrtz(e.x, e.y));
                u.w = __builtin_bit_cast(uint32_t, __builtin_amdgcn_cvt_pkrtz(e.z, e.w));
                slice[r * 8 + c] = u;
            }
        }
    }
    __syncthreads();
    const int w = tid >> 6, lane = tid & 63, grp = lane >> 3, c = lane & 7;
    const int* ibase = indices + t * (B_BATCH * L_BAG);
    const f16x8* slc = reinterpret_cast<const f16x8*>(slice) + c;
    f16x8 acc = (f16x8)(_Float16)0;
    for (int rep = 0; rep < REPB; ++rep) {
        int row = b0 + w * 8 + grp;
        for (int i = 0; i < HB / 64; ++i) {
            const int4* ib = reinterpret_cast<const int4*>(ibase + row * L_BAG);
            const int4 ia = ib[0];
            const int4 iz = ib[1];
            acc += slc[ia.x * 8]; acc += slc[ia.y * 8];
            acc += slc[ia.z * 8]; acc += slc[ia.w * 8];
            acc += slc[iz.x * 8]; acc += slc[iz.y * 8];
            acc += slc[iz.z * 8]; acc += slc[iz.w * 8];
            row += 64;
        }
    }
    // Keep the whole chain live; garbage, overwritten by the real kernel.
    float r0 = 0.f;
    #pragma unroll
    for (int k = 0; k < 8; ++k) r0 += (float)acc[k];
    out[bid * NTHR + tid] = r0;
}

// -------- real kernel: R11 verbatim (current best, 29.4 us) --------
__global__ __launch_bounds__(NTHR)
void EmbCatDense_53309134078326_kernel(
    const int*   __restrict__ indices,
    const float* __restrict__ to_cat,
    const float* __restrict__ tables,
    float*       __restrict__ out)
{
    __shared__ uint4 slice[V_VOCAB * 8];

    const int bid = blockIdx.x;
    const int tid = threadIdx.x;

    if (bid < GBLK) {
        const int h  = bid / TS;
        const int ts = bid - h * TS;
        const int t  = ts >> 1;
        const int s  = ts & 1;
        const int b0 = h * HB;
        {
            const int r0 = tid >> 3, c = tid & 7;
            const float* srcA = tables + (size_t)t * (V_VOCAB * D_DIM)
                              + s * 64 + c * 4;
            #pragma unroll 4
            for (int it = 0; it < 16; ++it) {
                const int r = it * 64 + r0;
                if (r < V_VOCAB) {
                    const float* pr = srcA + (size_t)r * D_DIM;
                    const f32x4 a = *reinterpret_cast<const f32x4*>(pr);
                    const f32x4 e = *reinterpret_cast<const f32x4*>(pr + 32);
                    uint4 u;
                    u.x = __builtin_bit_cast(uint32_t,
                              __builtin_amdgcn_cvt_pkrtz(a.x, a.y));
                    u.y = __builtin_bit_cast(uint32_t,
                              __builtin_amdgcn_cvt_pkrtz(a.z, a.w));
                    u.z = __builtin_bit_cast(uint32_t,
                              __builtin_amdgcn_cvt_pkrtz(e.x, e.y));
                    u.w = __builtin_bit_cast(uint32_t,
                              __builtin_amdgcn_cvt_pkrtz(e.z, e.w));
                    slice[r * 8 + c] = u;
                }
            }
        }
        __syncthreads();

        const int w    = tid >> 6;
        const int lane = tid & 63;
        const int grp  = lane >> 3;
        const int c    = lane & 7;
        const int* ibase = indices + t * (B_BATCH * L_BAG);
        const f16x8* slc = reinterpret_cast<const f16x8*>(slice) + c;
        f32x4* o4 = reinterpret_cast<f32x4*>(out)
                  + (size_t)(t + 1) * SEG4 + s * 16 + c;

        int row = b0 + w * 8 + grp;
        const int4* ib = reinterpret_cast<const int4*>(ibase + row * L_BAG);
        int4 ia = ib[0];
        int4 iz = ib[1];

        for (int i = 0; i < HB / 64; ++i) {
            int4 na = ia, nz = iz;
            if (i + 1 < HB / 64) {
                const int4* nb = reinterpret_cast<const int4*>(
                    ibase + (row + 64) * L_BAG);
                na = nb[0];
                nz = nb[1];
            }
            f16x8 acc = (f16x8)(_Float16)0;
            acc += slc[ia.x * 8]; acc += slc[ia.y * 8];
            acc += slc[ia.z * 8]; acc += slc[ia.w * 8];
            acc += slc[iz.x * 8]; acc += slc[iz.y * 8];
            acc += slc[iz.z * 8]; acc += slc[iz.w * 8];
            f32x4 vA, vB;
            vA.x = (float)acc[0]; vA.y = (float)acc[1];
            vA.z = (float)acc[2]; vA.w = (float)acc[3];
            vB.x = (float)acc[4]; vB.y = (float)acc[5];
            vB.z = (float)acc[6]; vB.w = (float)acc[7];
            o4[(size_t)row * ROW4]     = vA;
            o4[(size_t)row * ROW4 + 8] = vB;
            ia = na; iz = nz; row += 64;
        }
    } else {
        const int db = bid - GBLK;
        const f32x4* c4 = reinterpret_cast<const f32x4*>(to_cat);
        f32x4* o4 = reinterpret_cast<f32x4*>(out);
        for (int x = db * NTHR + tid; x < B_BATCH * SEG4; x += NDEN * NTHR) {
            const int r  = x >> 5;
            const int cc = x & 31;
            const f32x4 v = __builtin_nontemporal_load(&c4[x]);
            o4[(size_t)r * ROW4 + cc] = v;
        }
    }
}

extern "C" void kernel_launch(void* const* d_in, const int* in_sizes, int n_in,
                              void* d_out, int out_size, void* d_ws, size_t ws_size,
                              hipStream_t stream) {
    const int*   indices = (const int*)  d_in[0];
    // d_in[1] = offsets [T, B] — unused (fixed bag length L).
    const float* to_cat  = (const float*)d_in[2];
    const float* tables  = (const float*)d_in[3];
    float*       out     = (float*)      d_out;

    // Probes first (write garbage), real kernel LAST (overwrites everything).
    probe_store<<<NBLK, NTHR, 0, stream>>>(indices, to_cat, out);
    probe_lds  <<<NBLK, NTHR, 0, stream>>>(indices, tables, out);
    EmbCatDense_53309134078326_kernel<<<NBLK, NTHR, 0, stream>>>(
        indices, to_cat, tables, out);
}

// Round 13
// 29.598 us; speedup vs baseline: 8.3621x; 8.3621x over previous
//
#include <hip/hip_runtime.h>
#include <stdint.h>

// Problem constants (fixed by the reference).
#define T_TABLES 26
#define V_VOCAB  1000
#define D_DIM    128
#define B_BATCH  8192
#define L_BAG    8

#define SEG4   (D_DIM / 4)                   // 32 f32x4 per 128-float row
#define ROW4   ((T_TABLES + 1) * SEG4)       // 864 f32x4 per output row
#define NH     4                             // batch quarters per slice
#define HB     (B_BATCH / NH)                // 2048 rows per gather block
#define TS     (T_TABLES * 2)                // 52 (table, 64-dim-slice) pairs
#define GBLK   (TS * NH)                     // 208 gather blocks
#define NBLK   256                           // 1 block per CU
#define NDEN   (NBLK - GBLK)                 // 48 dense-copy blocks
#define NTHR   1024                          // 16 waves = 4 waves/SIMD

typedef float    f32x4 __attribute__((ext_vector_type(4)));
typedef _Float16 f16x8 __attribute__((ext_vector_type(8)));

// R13 = R11 at 1024 threads/block (4 waves/SIMD instead of 2).
// R12 ablation: store-side alone = 19.3 us/rep at ideal 110.5 MB writes
// (write wall, no amplification); full kernel = 29.4 = store + ~10 us of
// NON-overlapped gather. At 2 waves/SIMD both waves move in lockstep ->
// LDS-wait and store phases serialize. 4 waves/SIMD gives the scheduler
// independent waves to interleave LDS reads, VALU, and the store drain.
__global__ __launch_bounds__(NTHR)
void EmbCatDense_53309134078326_kernel(
    const int*   __restrict__ indices,   // [T, B, L] int32
    const float* __restrict__ to_cat,    // [B, D]
    const float* __restrict__ tables,    // [T, V, D]
    float*       __restrict__ out)       // [B, (T+1)*D]
{
    __shared__ uint4 slice[V_VOCAB * 8];     // 1000 rows x 64 fp16 = 125 KB

    const int bid = blockIdx.x;
    const int tid = threadIdx.x;

    if (bid < GBLK) {
        // ---- gather block: table t, 64-dim slice s, batch quarter h ----
        const int h  = bid / TS;             // batch quarter
        const int ts = bid - h * TS;
        const int t  = ts >> 1;
        const int s  = ts & 1;
        const int b0 = h * HB;

        // Stage tables[t, :, s*64 .. s*64+64) as fp16, swizzled:
        // chunk c <- dims {4c..4c+3, 32+4c..32+4c+3} (cvt_pkrtz).
        {
            const int r0 = tid >> 3, c = tid & 7;     // 128 rows per pass
            const float* srcA = tables + (size_t)t * (V_VOCAB * D_DIM)
                              + s * 64 + c * 4;       // dims 4c..4c+3
            #pragma unroll 4
            for (int it = 0; it < 8; ++it) {
                const int r = it * 128 + r0;
                if (r < V_VOCAB) {
                    const float* pr = srcA + (size_t)r * D_DIM;
                    const f32x4 a = *reinterpret_cast<const f32x4*>(pr);
                    const f32x4 e = *reinterpret_cast<const f32x4*>(pr + 32);
                    uint4 u;
                    u.x = __builtin_bit_cast(uint32_t,
                              __builtin_amdgcn_cvt_pkrtz(a.x, a.y));
                    u.y = __builtin_bit_cast(uint32_t,
                              __builtin_amdgcn_cvt_pkrtz(a.z, a.w));
                    u.z = __builtin_bit_cast(uint32_t,
                              __builtin_amdgcn_cvt_pkrtz(e.x, e.y));
                    u.w = __builtin_bit_cast(uint32_t,
                              __builtin_amdgcn_cvt_pkrtz(e.z, e.w));
                    slice[r * 8 + c] = u;
                }
            }
        }
        __syncthreads();

        const int w    = tid >> 6;           // wave 0..15
        const int lane = tid & 63;
        const int grp  = lane >> 3;          // 8 rows per wave-iter
        const int c    = lane & 7;           // 16 B chunk within slice row
        const int* ibase = indices + t * (B_BATCH * L_BAG);
        const f16x8* slc = reinterpret_cast<const f16x8*>(slice) + c;
        f32x4* o4 = reinterpret_cast<f32x4*>(out)
                  + (size_t)(t + 1) * SEG4 + s * 16 + c;

        // Depth-1 pipelined index loads (32 B per 8-lane group, L2-hot).
        int row = b0 + w * 8 + grp;
        const int4* ib = reinterpret_cast<const int4*>(ibase + row * L_BAG);
        int4 ia = ib[0];
        int4 iz = ib[1];

        for (int i = 0; i < HB / 128; ++i) { // 16 iters, 128 rows/block/iter
            int4 na = ia, nz = iz;
            if (i + 1 < HB / 128) {
                const int4* nb = reinterpret_cast<const int4*>(
                    ibase + (row + 128) * L_BAG);
                na = nb[0];
                nz = nb[1];
            }
            f16x8 acc = (f16x8)(_Float16)0;  // 4x v_pk_add_f16 per bag
            acc += slc[ia.x * 8]; acc += slc[ia.y * 8];
            acc += slc[ia.z * 8]; acc += slc[ia.w * 8];
            acc += slc[iz.x * 8]; acc += slc[iz.y * 8];
            acc += slc[iz.z * 8]; acc += slc[iz.w * 8];
            f32x4 vA, vB;                    // un-swizzle at store time
            vA.x = (float)acc[0]; vA.y = (float)acc[1];
            vA.z = (float)acc[2]; vA.w = (float)acc[3];   // dims 4c..4c+3
            vB.x = (float)acc[4]; vB.y = (float)acc[5];
            vB.z = (float)acc[6]; vB.w = (float)acc[7];   // dims 32+4c..+3
            // 8 lanes x 16 B dense 128 B runs (R6's proven pattern).
            o4[(size_t)row * ROW4]     = vA;
            o4[(size_t)row * ROW4 + 8] = vB;
            ia = na; iz = nz; row += 128;
        }
    } else {
        // ---- dense to_cat copy: 48 blocks, grid-stride ----
        const int db = bid - GBLK;
        const f32x4* c4 = reinterpret_cast<const f32x4*>(to_cat);
        f32x4* o4 = reinterpret_cast<f32x4*>(out);
        for (int x = db * NTHR + tid; x < B_BATCH * SEG4; x += NDEN * NTHR) {
            const int r  = x >> 5;           // x / SEG4
            const int cc = x & 31;
            const f32x4 v = __builtin_nontemporal_load(&c4[x]);
            o4[(size_t)r * ROW4 + cc] = v;
        }
    }
}

extern "C" void kernel_launch(void* const* d_in, const int* in_sizes, int n_in,
                              void* d_out, int out_size, void* d_ws, size_t ws_size,
                              hipStream_t stream) {
    const int*   indices = (const int*)  d_in[0];
    // d_in[1] = offsets [T, B] — encodes fixed bag length L, unused.
    const float* to_cat  = (const float*)d_in[2];
    const float* tables  = (const float*)d_in[3];
    float*       out     = (float*)      d_out;

    EmbCatDense_53309134078326_kernel<<<NBLK, NTHR, 0, stream>>>(
        indices, to_cat, tables, out);
}